// Round 6
// baseline (276.019 us; speedup 1.0000x reference)
//
#include <hip/hip_runtime.h>
#include <hip/hip_bf16.h>
#include <math.h>

#define N_NODES 50000
#define N_EDGES 800000
#define ET_EDGES (N_EDGES + N_NODES)   // with self-loops
#define NEG_SLOPE 0.2f
#define NBUCK ((N_NODES + 255) / 256)  // 196 dst buckets (256 nodes each)
#define CHUNK 4096                      // edges per binning block
#define CAP   8192                      // scratch slots per bucket (>50 sigma)

typedef __hip_bfloat16 bf16;
typedef float f32x2 __attribute__((ext_vector_type(2)));

__device__ inline float bfbits(unsigned short u) {
    return __uint_as_float(((unsigned)u) << 16);
}
__device__ inline float bflo(unsigned u) { return __uint_as_float(u << 16); }
__device__ inline float bfhi(unsigned u) { return __uint_as_float(u & 0xffff0000u); }
__device__ inline f32x2 unpk(unsigned u) {
    f32x2 r; r.x = bflo(u); r.y = bfhi(u); return r;
}
__device__ inline f32x2 bcast2(float v) { f32x2 r; r.x = v; r.y = v; return r; }

// ---------------- prep: convert params (parallel) + init cursors + flag -----
struct PrepArgs {
    const void* src[12];
    float*      dst[12];
    int         n[12];
};

__global__ __launch_bounds__(256)
void prep(PrepArgs a, const unsigned short* __restrict__ w1raw,
          unsigned* __restrict__ flag, int* __restrict__ cur256)
{
    __shared__ unsigned sflag;
    const int tid = threadIdx.x;
    if (tid < 64) {
        float v0 = bfbits(w1raw[2 * tid]);
        float v1 = bfbits(w1raw[2 * tid + 1]);
        bool bad = !(fabsf(v0) <= 64.f && fabsf(v1) <= 64.f);  // NaN -> bad
        unsigned long long b = __ballot(bad);
        if (tid == 0) sflag = (b == 0ull) ? 1u : 0u;
    }
    __syncthreads();
    const bool isbf = (sflag != 0u);
    const int which = blockIdx.y;

    if (which == 12) {
        int i = blockIdx.x * 256 + tid;
        if (i < NBUCK) cur256[i] = i * CAP;
        if (blockIdx.x == 0 && tid == 0) *flag = isbf ? 1u : 0u;
        return;
    }
    const int n = a.n[which];
    const void* s = a.src[which];
    float* d = a.dst[which];
    for (int i = blockIdx.x * 256 + tid; i < n; i += 8 * 256)
        d[i] = isbf ? bfbits(((const unsigned short*)s)[i])
                    : ((const float*)s)[i];
}

// ---------------- Pass C: bin edges into per-bucket scratch segments --------
__global__ __launch_bounds__(256)
void binpass(const int* __restrict__ ei, int* __restrict__ cur256,
             unsigned* __restrict__ scratch)
{
    __shared__ int hist[NBUCK];
    __shared__ int lpre[NBUCK + 1];
    __shared__ int lcur[NBUCK];
    __shared__ int gbase[NBUCK];
    __shared__ int scan_a[256];
    __shared__ unsigned entry[CHUNK];

    const int tid = threadIdx.x;
    const int e0  = blockIdx.x * CHUNK;
    const int n   = min(CHUNK, ET_EDGES - e0);

    if (tid < NBUCK) hist[tid] = 0;
    __syncthreads();

    for (int k = tid; k < n; k += 256) {
        int e = e0 + k;
        int d = (e < N_EDGES) ? ei[N_EDGES + e] : e - N_EDGES;
        atomicAdd(&hist[d >> 8], 1);
    }
    __syncthreads();

    int v = (tid < NBUCK) ? hist[tid] : 0;
    scan_a[tid] = v;
    __syncthreads();
    for (int off = 1; off < 256; off <<= 1) {
        int t = (tid >= off) ? scan_a[tid - off] : 0;
        __syncthreads();
        scan_a[tid] += t;
        __syncthreads();
    }
    if (tid < NBUCK) lpre[tid] = scan_a[tid] - v;
    if (tid == NBUCK - 1) lpre[NBUCK] = scan_a[tid];
    if (tid < NBUCK) {
        gbase[tid] = v ? atomicAdd(&cur256[tid], v) : 0;
        lcur[tid] = 0;
    }
    __syncthreads();

    for (int k = tid; k < n; k += 256) {
        int e = e0 + k;
        int s, d;
        if (e < N_EDGES) { s = ei[e]; d = ei[N_EDGES + e]; }
        else             { s = d = e - N_EDGES; }
        int b = d >> 8;
        int p = atomicAdd(&lcur[b], 1);
        entry[lpre[b] + p] = ((unsigned)s << 8) | (unsigned)(d & 255);
    }
    __syncthreads();

    for (int i = tid; i < n; i += 256) {
        int lo = 0, hi = NBUCK;
        while (hi - lo > 1) {
            int mid = (lo + hi) >> 1;
            if (lpre[mid] <= i) lo = mid; else hi = mid;
        }
        scratch[gbase[lo] + (i - lpre[lo])] = entry[i];
    }
}

// Pass D: inline bucket scan -> per-bucket node count/prefix -> rowptr +
// LDS-cursor scatter. R6: also emits csr_dst (needed by edge_w).
__global__ __launch_bounds__(256)
void fine_scatter(const int* __restrict__ cur256,
                  const unsigned* __restrict__ scratch,
                  int* __restrict__ csr_src,
                  int* __restrict__ csr_dst,
                  int* __restrict__ rowptr)
{
    __shared__ int scnt[256];
    __shared__ int cnt[256];
    __shared__ int pre[256];
    const int tid = threadIdx.x;
    const int b   = blockIdx.x;
    const int nb  = b * 256;
    const int nn  = min(256, N_NODES - nb);

    // inline exclusive scan over realized bucket counts
    int bv = (tid < NBUCK) ? (cur256[tid] - tid * CAP) : 0;
    scnt[tid] = bv;
    __syncthreads();
    for (int off = 1; off < 256; off <<= 1) {
        int u = (tid >= off) ? scnt[tid - off] : 0;
        __syncthreads();
        scnt[tid] += u;
        __syncthreads();
    }
    const int gb = scnt[b] - (cur256[b] - b * CAP);   // exclusive prefix at b
    const int n  = cur256[b] - b * CAP;               // realized count
    const long seg = (long)b * CAP;

    cnt[tid] = 0;
    __syncthreads();
    for (int i = tid; i < n; i += 256)
        atomicAdd(&cnt[scratch[seg + i] & 255u], 1);
    __syncthreads();

    int v = cnt[tid];
    pre[tid] = v;
    __syncthreads();
    for (int off = 1; off < 256; off <<= 1) {
        int t = (tid >= off) ? pre[tid - off] : 0;
        __syncthreads();
        pre[tid] += t;
        __syncthreads();
    }
    int excl = pre[tid] - v + gb;
    if (tid < nn) rowptr[nb + tid] = excl;
    if (b == NBUCK - 1 && tid == 0) rowptr[N_NODES] = ET_EDGES;
    cnt[tid] = excl;    // reuse as cursors
    __syncthreads();

    for (int i = tid; i < n; i += 256) {
        unsigned e = scratch[seg + i];
        int p = atomicAdd(&cnt[e & 255u], 1);
        csr_src[p] = (int)(e >> 8);
        csr_dst[p] = nb + (int)(e & 255u);
    }
}

// ---------------- edge_w: per-edge unnormalized softmax weight --------------
// R6: hoists the leaky+exp weight computation out of gat_gather (which was
// DS-shuffle-bound broadcasting these values). Edge-parallel, coalesced
// 16B streams; as_/ad_ gathers are L2-resident (0.2MB each, dst nearly
// sequential since CSR is dst-sorted).
__global__ __launch_bounds__(256)
void edge_w(const int* __restrict__ csr_src, const int* __restrict__ csr_dst,
            const float* __restrict__ as_, const float* __restrict__ ad_,
            float* __restrict__ ew)
{
    const int i = (blockIdx.x * 256 + threadIdx.x) * 4;
    if (i >= ET_EDGES) return;     // ET_EDGES % 4 == 0
    const int4 s4 = *(const int4*)&csr_src[i];
    const int4 d4 = *(const int4*)&csr_dst[i];
    float v0 = as_[s4.x] + ad_[d4.x];
    float v1 = as_[s4.y] + ad_[d4.y];
    float v2 = as_[s4.z] + ad_[d4.z];
    float v3 = as_[s4.w] + ad_[d4.w];
    v0 = (v0 > 0.f) ? v0 : NEG_SLOPE * v0;
    v1 = (v1 > 0.f) ? v1 : NEG_SLOPE * v1;
    v2 = (v2 > 0.f) ? v2 : NEG_SLOPE * v2;
    v3 = (v3 > 0.f) ? v3 : NEG_SLOPE * v3;
    float4 w;
    w.x = __expf(fminf(v0, 60.f));
    w.y = __expf(fminf(v1, 60.f));
    w.z = __expf(fminf(v2, 60.f));
    w.w = __expf(fminf(v3, 60.f));
    *(float4*)&ew[i] = w;
}

// ---------------- GAT gather: 16-lane group/node, precomputed weights -------
// R6: zero cross-lane ops in the main loop. (src, w) come straight from
// csr_src/ew; the 8 channel-lanes of a group read the SAME address (HW
// same-address broadcast, 16 distinct addrs per wave instr). Uniform degree
// loop (no 32-edge banks, no tail special case). Payload gather keeps the
// known-good 4-uint4-in-flight predicated form.
#define EDGE4_FMA(wX, pX) {                                                  \
    f32x2 w2_ = { wX, wX };                                                  \
    A0 = __builtin_elementwise_fma(w2_, unpk(pX.x), A0);                     \
    A1 = __builtin_elementwise_fma(w2_, unpk(pX.y), A1);                     \
    A2 = __builtin_elementwise_fma(w2_, unpk(pX.z), A2);                     \
    A3 = __builtin_elementwise_fma(w2_, unpk(pX.w), A3); }

template<bool DO_ELU, int OMODE>
__global__ __launch_bounds__(256)
void gat_gather(const int* __restrict__ rowptr,
                const int* __restrict__ csr_src,
                const float* __restrict__ ew,
                const unsigned short* __restrict__ hb_in,
                const float* __restrict__ bias,
                void* __restrict__ out,
                const unsigned* __restrict__ flag)
{
    const int tid  = threadIdx.x;
    const int lane = tid & 63;
    const int l16  = lane & 15;
    const int sub  = l16 >> 3;                     // edge parity slot 0/1
    const int c8   = (l16 & 7) * 8;                // channel group
    const int node = blockIdx.x * 16 + (tid >> 4); // 16 nodes per block
    if (node >= N_NODES) return;

    const int beg = rowptr[node];
    const int deg = rowptr[node + 1] - beg;

    f32x2 A0 = {0.f, 0.f}, A1 = {0.f, 0.f}, A2 = {0.f, 0.f}, A3 = {0.f, 0.f};
    float dsum = 0.f;

    for (int j0 = 0; j0 < deg; j0 += 8) {
        const int jA = j0 + sub,     jB = j0 + 2 + sub;
        const int jC = j0 + 4 + sub, jD = j0 + 6 + sub;
        const bool vA = jA < deg, vB = jB < deg, vC = jC < deg, vD = jD < deg;
        int sA = 0, sB = 0, sC = 0, sD = 0;
        float wA = 0.f, wB = 0.f, wC = 0.f, wD = 0.f;
        if (vA) { sA = csr_src[beg + jA]; wA = ew[beg + jA]; }
        if (vB) { sB = csr_src[beg + jB]; wB = ew[beg + jB]; }
        if (vC) { sC = csr_src[beg + jC]; wC = ew[beg + jC]; }
        if (vD) { sD = csr_src[beg + jD]; wD = ew[beg + jD]; }
        uint4 pA={0u,0u,0u,0u}, pB={0u,0u,0u,0u}, pC={0u,0u,0u,0u}, pD={0u,0u,0u,0u};
        if (vA) pA = *(const uint4*)&hb_in[(long)sA * 64 + c8];
        if (vB) pB = *(const uint4*)&hb_in[(long)sB * 64 + c8];
        if (vC) pC = *(const uint4*)&hb_in[(long)sC * 64 + c8];
        if (vD) pD = *(const uint4*)&hb_in[(long)sD * 64 + c8];
        EDGE4_FMA(wA, pA) EDGE4_FMA(wB, pB) EDGE4_FMA(wC, pC) EDGE4_FMA(wD, pD)
        dsum += (wA + wB) + (wC + wD);
    }

    float a0 = A0.x, a1 = A0.y, a2 = A1.x, a3 = A1.y;
    float a4 = A2.x, a5 = A2.y, a6 = A3.x, a7 = A3.y;
    a0 += __shfl_xor(a0, 8, 64); a1 += __shfl_xor(a1, 8, 64);
    a2 += __shfl_xor(a2, 8, 64); a3 += __shfl_xor(a3, 8, 64);
    a4 += __shfl_xor(a4, 8, 64); a5 += __shfl_xor(a5, 8, 64);
    a6 += __shfl_xor(a6, 8, 64); a7 += __shfl_xor(a7, 8, 64);
    dsum += __shfl_xor(dsum, 8, 64);

    if (sub == 0) {   // lanes l16 0..7 hold channels c8..c8+7
        float inv = 1.f / dsum;
        float r[8] = {a0, a1, a2, a3, a4, a5, a6, a7};
#pragma unroll
        for (int k = 0; k < 8; ++k) {
            r[k] = r[k] * inv + bias[c8 + k];
            if (DO_ELU) r[k] = (r[k] > 0.f) ? r[k] : expm1f(r[k]);
        }
        long o = (long)node * 64 + c8;
        bool bfst = (OMODE == 0) || (*flag != 0u);
        if (bfst) {
            uint4 u;
            u.x = ((unsigned)__bfloat16_as_ushort(__float2bfloat16(r[0]))) |
                  (((unsigned)__bfloat16_as_ushort(__float2bfloat16(r[1]))) << 16);
            u.y = ((unsigned)__bfloat16_as_ushort(__float2bfloat16(r[2]))) |
                  (((unsigned)__bfloat16_as_ushort(__float2bfloat16(r[3]))) << 16);
            u.z = ((unsigned)__bfloat16_as_ushort(__float2bfloat16(r[4]))) |
                  (((unsigned)__bfloat16_as_ushort(__float2bfloat16(r[5]))) << 16);
            u.w = ((unsigned)__bfloat16_as_ushort(__float2bfloat16(r[6]))) |
                  (((unsigned)__bfloat16_as_ushort(__float2bfloat16(r[7]))) << 16);
            *(uint4*)&((unsigned short*)out)[o] = u;
        } else {
            float4 f0 = {r[0], r[1], r[2], r[3]};
            float4 f1 = {r[4], r[5], r[6], r[7]};
            *(float4*)&((float*)out)[o]     = f0;
            *(float4*)&((float*)out)[o + 4] = f1;
        }
    }
}

// ---------------- GEMM + alpha epilogue -------------------------------------
// (unchanged from R5: 64x64 register-blocked, `#pragma unroll 2` discipline)
template<int CIN, int XMODE>
__global__ __launch_bounds__(256)
void gemm_alpha(const void* __restrict__ x,
                const float* __restrict__ W,
                const float* __restrict__ a_src,
                const float* __restrict__ a_dst,
                const unsigned* __restrict__ flag,
                bf16* __restrict__ hb,
                float* __restrict__ as_out,
                float* __restrict__ ad_out)
{
    constexpr int CINP = CIN + 4;            // pad: keeps 16B align, 2-way banks
    __shared__ float sW[CIN * 64];           // natural [k][c]
    __shared__ float sx[64 * CINP];          // [row][k], padded
    const bool isbf = (XMODE == 2) || (XMODE == 1 && *flag != 0u);
    const int tid  = threadIdx.x;
    const int colg = tid & 15;               // 16 col groups x 4 cols
    const int rowg = tid >> 4;               // 16 row groups x 4 rows
    const int c0   = colg * 4;
    const int r0l  = rowg * 4;
    const int row0 = blockIdx.x * 64;

    for (int i = tid * 4; i < CIN * 64; i += 1024)
        *(float4*)&sW[i] = *(const float4*)&W[i];

    const long xbase = (long)row0 * CIN;
    const int  tile  = 64 * CIN;
    const int  limit = (N_NODES - row0) * CIN;   // multiple of 4
    if (isbf) {
        const unsigned short* xb = (const unsigned short*)x + xbase;
        for (int i = tid * 4; i < tile; i += 1024) {
            float4 v = {0.f, 0.f, 0.f, 0.f};
            if (i < limit) {
                ushort4 u = *(const ushort4*)&xb[i];
                v.x = bfbits(u.x); v.y = bfbits(u.y);
                v.z = bfbits(u.z); v.w = bfbits(u.w);
            }
            const int r = i / CIN, k = i & (CIN - 1);
            *(float4*)&sx[r * CINP + k] = v;
        }
    } else {
        const float* xf = (const float*)x + xbase;
        for (int i = tid * 4; i < tile; i += 1024) {
            float4 v = {0.f, 0.f, 0.f, 0.f};
            if (i < limit) v = *(const float4*)&xf[i];
            const int r = i / CIN, k = i & (CIN - 1);
            *(float4*)&sx[r * CINP + k] = v;
        }
    }
    __syncthreads();

    f32x2 acc[4][2];
#pragma unroll
    for (int r = 0; r < 4; ++r) {
        acc[r][0] = (f32x2){0.f, 0.f};
        acc[r][1] = (f32x2){0.f, 0.f};
    }

#pragma unroll 2
    for (int kk = 0; kk < CIN; kk += 4) {
        const float4 w0 = *(const float4*)&sW[(kk + 0) * 64 + c0];
        const float4 w1 = *(const float4*)&sW[(kk + 1) * 64 + c0];
        const float4 w2 = *(const float4*)&sW[(kk + 2) * 64 + c0];
        const float4 w3 = *(const float4*)&sW[(kk + 3) * 64 + c0];
        f32x2 w0lo; w0lo.x = w0.x; w0lo.y = w0.y;
        f32x2 w0hi; w0hi.x = w0.z; w0hi.y = w0.w;
        f32x2 w1lo; w1lo.x = w1.x; w1lo.y = w1.y;
        f32x2 w1hi; w1hi.x = w1.z; w1hi.y = w1.w;
        f32x2 w2lo; w2lo.x = w2.x; w2lo.y = w2.y;
        f32x2 w2hi; w2hi.x = w2.z; w2hi.y = w2.w;
        f32x2 w3lo; w3lo.x = w3.x; w3lo.y = w3.y;
        f32x2 w3hi; w3hi.x = w3.z; w3hi.y = w3.w;
#pragma unroll
        for (int r = 0; r < 4; ++r) {
            const float4 xv = *(const float4*)&sx[(r0l + r) * CINP + kk];
            acc[r][0] = __builtin_elementwise_fma(bcast2(xv.x), w0lo, acc[r][0]);
            acc[r][1] = __builtin_elementwise_fma(bcast2(xv.x), w0hi, acc[r][1]);
            acc[r][0] = __builtin_elementwise_fma(bcast2(xv.y), w1lo, acc[r][0]);
            acc[r][1] = __builtin_elementwise_fma(bcast2(xv.y), w1hi, acc[r][1]);
            acc[r][0] = __builtin_elementwise_fma(bcast2(xv.z), w2lo, acc[r][0]);
            acc[r][1] = __builtin_elementwise_fma(bcast2(xv.z), w2hi, acc[r][1]);
            acc[r][0] = __builtin_elementwise_fma(bcast2(xv.w), w3lo, acc[r][0]);
            acc[r][1] = __builtin_elementwise_fma(bcast2(xv.w), w3hi, acc[r][1]);
        }
    }

    const float4 sa4 = *(const float4*)&a_src[c0];
    const float4 sd4 = *(const float4*)&a_dst[c0];
#pragma unroll
    for (int r = 0; r < 4; ++r) {
        const int row = row0 + r0l + r;
        const float h0 = acc[r][0].x, h1 = acc[r][0].y;
        const float h2 = acc[r][1].x, h3 = acc[r][1].y;
        float vs = fmaf(h0, sa4.x, fmaf(h1, sa4.y, fmaf(h2, sa4.z, h3 * sa4.w)));
        float vd = fmaf(h0, sd4.x, fmaf(h1, sd4.y, fmaf(h2, sd4.z, h3 * sd4.w)));
#pragma unroll
        for (int off = 1; off < 16; off <<= 1) {
            vs += __shfl_xor(vs, off, 64);
            vd += __shfl_xor(vd, off, 64);
        }
        if (row < N_NODES) {
            uint2 u;
            u.x = ((unsigned)__bfloat16_as_ushort(__float2bfloat16(h0))) |
                  (((unsigned)__bfloat16_as_ushort(__float2bfloat16(h1))) << 16);
            u.y = ((unsigned)__bfloat16_as_ushort(__float2bfloat16(h2))) |
                  (((unsigned)__bfloat16_as_ushort(__float2bfloat16(h3))) << 16);
            *(uint2*)&((unsigned short*)hb)[(long)row * 64 + c0] = u;
            if (colg == 0) { as_out[row] = vs; ad_out[row] = vd; }
        }
    }
}

extern "C" void kernel_launch(void* const* d_in, const int* in_sizes, int n_in,
                              void* d_out, int out_size, void* d_ws, size_t ws_size,
                              hipStream_t stream)
{
    const void* x  = d_in[0];
    const int*  ei = (const int*)d_in[1];
    const void* pW1 = d_in[2],  *pas1 = d_in[3],  *pad1 = d_in[4],  *pb1 = d_in[5];
    const void* pW2 = d_in[6],  *pas2 = d_in[7],  *pad2 = d_in[8],  *pb2 = d_in[9];
    const void* pW3 = d_in[10], *pas3 = d_in[11], *pad3 = d_in[12], *pb3 = d_in[13];

    float* ws = (float*)d_ws;
    bf16*     hbA    = (bf16*)ws;                              // 6.4 MB
    bf16*     hbB    = (bf16*)(ws + (long)N_NODES * 32);       // 6.4 MB
    float*    as_    = ws + (long)N_NODES * 64;
    float*    ad_    = as_ + N_NODES;
    int*      cur256 = (int*)(ad_ + N_NODES);                  // NBUCK
    int*      rowptr = cur256 + NBUCK;                         // N+1
    int*      csr_src= rowptr + N_NODES + 1;                   // 3.4 MB
    int*      csr_dst= csr_src + ET_EDGES;                     // 3.4 MB
    unsigned* scratch= (unsigned*)(csr_dst + ET_EDGES);        // NBUCK*CAP 6.4 MB
    float*    ew     = (float*)(scratch + (long)NBUCK * CAP);  // 3.4 MB
    float*    prm    = ew + ET_EDGES;
    unsigned* flag   = (unsigned*)(prm + 20000);

    float* W1 = prm;     float* as1 = W1 + 8192; float* ad1 = as1 + 64; float* b1 = ad1 + 64;
    float* W2 = b1 + 64; float* as2 = W2 + 4096; float* ad2 = as2 + 64; float* b2 = ad2 + 64;
    float* W3 = b2 + 64; float* as3 = W3 + 4096; float* ad3 = as3 + 64; float* b3 = ad3 + 64;

    PrepArgs pa;
    const void* srcs[12] = {pW1, pas1, pad1, pb1, pW2, pas2, pad2, pb2, pW3, pas3, pad3, pb3};
    float*      dsts[12] = {W1, as1, ad1, b1, W2, as2, ad2, b2, W3, as3, ad3, b3};
    int         ns[12]   = {8192, 64, 64, 64, 4096, 64, 64, 64, 4096, 64, 64, 64};
    for (int i = 0; i < 12; ++i) { pa.src[i] = srcs[i]; pa.dst[i] = dsts[i]; pa.n[i] = ns[i]; }
    prep<<<dim3(8, 13), 256, 0, stream>>>(pa, (const unsigned short*)pW1, flag, cur256);

    // ---- CSR build: segment-append binpass -> fine scatter (inline scan) ----
    const int chunk_grid = (ET_EDGES + CHUNK - 1) / CHUNK;
    binpass<<<chunk_grid, 256, 0, stream>>>(ei, cur256, scratch);
    fine_scatter<<<NBUCK, 256, 0, stream>>>(cur256, scratch, csr_src, csr_dst, rowptr);

    const int gemm_grid = (N_NODES + 63) / 64;
    const int gat_grid  = (N_NODES + 15) / 16;
    const int ew_grid   = (ET_EDGES / 4 + 255) / 256;

    // ---------- Layer 1 ----------
    gemm_alpha<128, 1><<<gemm_grid, 256, 0, stream>>>(
        x, W1, as1, ad1, flag, hbA, as_, ad_);
    edge_w<<<ew_grid, 256, 0, stream>>>(csr_src, csr_dst, as_, ad_, ew);
    gat_gather<true, 0><<<gat_grid, 256, 0, stream>>>(
        rowptr, csr_src, ew, (const unsigned short*)hbA, b1, hbB, flag);

    // ---------- Layer 2 (bf16 layer io) ----------
    gemm_alpha<64, 2><<<gemm_grid, 256, 0, stream>>>(
        hbB, W2, as2, ad2, flag, hbA, as_, ad_);
    edge_w<<<ew_grid, 256, 0, stream>>>(csr_src, csr_dst, as_, ad_, ew);
    gat_gather<true, 0><<<gat_grid, 256, 0, stream>>>(
        rowptr, csr_src, ew, (const unsigned short*)hbA, b2, hbB, flag);

    // ---------- Layer 3 ----------
    gemm_alpha<64, 2><<<gemm_grid, 256, 0, stream>>>(
        hbB, W3, as3, ad3, flag, hbA, as_, ad_);
    edge_w<<<ew_grid, 256, 0, stream>>>(csr_src, csr_dst, as_, ad_, ew);
    gat_gather<false, 1><<<gat_grid, 256, 0, stream>>>(
        rowptr, csr_src, ew, (const unsigned short*)hbA, b3, d_out, flag);
}

// Round 7
// 234.418 us; speedup vs baseline: 1.1775x; 1.1775x over previous
//
#include <hip/hip_runtime.h>
#include <hip/hip_bf16.h>
#include <math.h>

#define N_NODES 50000
#define N_EDGES 800000
#define ET_EDGES (N_EDGES + N_NODES)   // with self-loops
#define NEG_SLOPE 0.2f
#define NBUCK ((N_NODES + 255) / 256)  // 196 dst buckets (256 nodes each)
#define CHUNK 4096                      // edges per binning block
#define CAP   8192                      // scratch slots per bucket (>50 sigma)
#define BIN_GRID ((ET_EDGES + CHUNK - 1) / CHUNK)   // 208
#define GEMM_GRID ((N_NODES + 63) / 64)             // 782

typedef __hip_bfloat16 bf16;
typedef float f32x2 __attribute__((ext_vector_type(2)));

__device__ inline float bfbits(unsigned short u) {
    return __uint_as_float(((unsigned)u) << 16);
}
__device__ inline float bflo(unsigned u) { return __uint_as_float(u << 16); }
__device__ inline float bfhi(unsigned u) { return __uint_as_float(u & 0xffff0000u); }
__device__ inline f32x2 unpk(unsigned u) {
    f32x2 r; r.x = bflo(u); r.y = bfhi(u); return r;
}
__device__ inline f32x2 bcast2(float v) { f32x2 r; r.x = v; r.y = v; return r; }

// ---------------- prep: convert params (parallel) + init cursors + flag -----
struct PrepArgs {
    const void* src[12];
    float*      dst[12];
    int         n[12];
};

__global__ __launch_bounds__(256)
void prep(PrepArgs a, const unsigned short* __restrict__ w1raw,
          unsigned* __restrict__ flag, int* __restrict__ cur256)
{
    __shared__ unsigned sflag;
    const int tid = threadIdx.x;
    if (tid < 64) {
        float v0 = bfbits(w1raw[2 * tid]);
        float v1 = bfbits(w1raw[2 * tid + 1]);
        bool bad = !(fabsf(v0) <= 64.f && fabsf(v1) <= 64.f);  // NaN -> bad
        unsigned long long b = __ballot(bad);
        if (tid == 0) sflag = (b == 0ull) ? 1u : 0u;
    }
    __syncthreads();
    const bool isbf = (sflag != 0u);
    const int which = blockIdx.y;

    if (which == 12) {
        int i = blockIdx.x * 256 + tid;
        if (i < NBUCK) cur256[i] = i * CAP;
        if (blockIdx.x == 0 && tid == 0) *flag = isbf ? 1u : 0u;
        return;
    }
    const int n = a.n[which];
    const void* s = a.src[which];
    float* d = a.dst[which];
    for (int i = blockIdx.x * 256 + tid; i < n; i += 8 * 256)
        d[i] = isbf ? bfbits(((const unsigned short*)s)[i])
                    : ((const float*)s)[i];
}

// ---------------- binpass body (device fn; fused with gemm1) ----------------
__device__ void binpass_body(unsigned char* smem, int bid,
                             const int* __restrict__ ei,
                             int* __restrict__ cur256,
                             unsigned* __restrict__ scratch)
{
    int* hist   = (int*)smem;                  // 196
    int* lpre   = hist + NBUCK;                // 197
    int* lcur   = lpre + NBUCK + 1;            // 196
    int* gbase  = lcur + NBUCK;                // 196
    int* scan_a = gbase + NBUCK;               // 256
    unsigned* entry = (unsigned*)(scan_a + 256); // 4096

    const int tid = threadIdx.x;
    const int e0  = bid * CHUNK;
    const int n   = min(CHUNK, ET_EDGES - e0);

    if (tid < NBUCK) hist[tid] = 0;
    __syncthreads();

    for (int k = tid; k < n; k += 256) {
        int e = e0 + k;
        int d = (e < N_EDGES) ? ei[N_EDGES + e] : e - N_EDGES;
        atomicAdd(&hist[d >> 8], 1);
    }
    __syncthreads();

    int v = (tid < NBUCK) ? hist[tid] : 0;
    scan_a[tid] = v;
    __syncthreads();
    for (int off = 1; off < 256; off <<= 1) {
        int t = (tid >= off) ? scan_a[tid - off] : 0;
        __syncthreads();
        scan_a[tid] += t;
        __syncthreads();
    }
    if (tid < NBUCK) lpre[tid] = scan_a[tid] - v;
    if (tid == NBUCK - 1) lpre[NBUCK] = scan_a[tid];
    if (tid < NBUCK) {
        gbase[tid] = v ? atomicAdd(&cur256[tid], v) : 0;
        lcur[tid] = 0;
    }
    __syncthreads();

    for (int k = tid; k < n; k += 256) {
        int e = e0 + k;
        int s, d;
        if (e < N_EDGES) { s = ei[e]; d = ei[N_EDGES + e]; }
        else             { s = d = e - N_EDGES; }
        int b = d >> 8;
        int p = atomicAdd(&lcur[b], 1);
        entry[lpre[b] + p] = ((unsigned)s << 8) | (unsigned)(d & 255);
    }
    __syncthreads();

    for (int i = tid; i < n; i += 256) {
        int lo = 0, hi = NBUCK;
        while (hi - lo > 1) {
            int mid = (lo + hi) >> 1;
            if (lpre[mid] <= i) lo = mid; else hi = mid;
        }
        scratch[gbase[lo] + (i - lpre[lo])] = entry[i];
    }
}

// Pass D: inline bucket scan -> per-bucket node count/prefix -> rowptr +
// LDS-cursor scatter. (unchanged from R5)
__global__ __launch_bounds__(256)
void fine_scatter(const int* __restrict__ cur256,
                  const unsigned* __restrict__ scratch,
                  int* __restrict__ csr_src,
                  int* __restrict__ rowptr)
{
    __shared__ int scnt[256];
    __shared__ int cnt[256];
    __shared__ int pre[256];
    const int tid = threadIdx.x;
    const int b   = blockIdx.x;
    const int nb  = b * 256;
    const int nn  = min(256, N_NODES - nb);

    int bv = (tid < NBUCK) ? (cur256[tid] - tid * CAP) : 0;
    scnt[tid] = bv;
    __syncthreads();
    for (int off = 1; off < 256; off <<= 1) {
        int u = (tid >= off) ? scnt[tid - off] : 0;
        __syncthreads();
        scnt[tid] += u;
        __syncthreads();
    }
    const int gb = scnt[b] - (cur256[b] - b * CAP);   // exclusive prefix at b
    const int n  = cur256[b] - b * CAP;               // realized count
    const long seg = (long)b * CAP;

    cnt[tid] = 0;
    __syncthreads();
    for (int i = tid; i < n; i += 256)
        atomicAdd(&cnt[scratch[seg + i] & 255u], 1);
    __syncthreads();

    int v = cnt[tid];
    pre[tid] = v;
    __syncthreads();
    for (int off = 1; off < 256; off <<= 1) {
        int t = (tid >= off) ? pre[tid - off] : 0;
        __syncthreads();
        pre[tid] += t;
        __syncthreads();
    }
    int excl = pre[tid] - v + gb;
    if (tid < nn) rowptr[nb + tid] = excl;
    if (b == NBUCK - 1 && tid == 0) rowptr[N_NODES] = ET_EDGES;
    cnt[tid] = excl;    // reuse as cursors
    __syncthreads();

    for (int i = tid; i < n; i += 256) {
        unsigned e = scratch[seg + i];
        int p = atomicAdd(&cnt[e & 255u], 1);
        csr_src[p] = (int)(e >> 8);
    }
}

// ---------------- GEMM + alpha epilogue body (device fn) --------------------
// R5-proven: 64x64 register-blocked, 4x4 per thread, `#pragma unroll 2`.
template<int CIN, int XMODE>
__device__ void gemm_body(unsigned char* smem, int bid,
                          const void* __restrict__ x,
                          const float* __restrict__ W,
                          const float* __restrict__ a_src,
                          const float* __restrict__ a_dst,
                          const unsigned* __restrict__ flag,
                          bf16* __restrict__ hb,
                          float* __restrict__ as_out,
                          float* __restrict__ ad_out)
{
    constexpr int CINP = CIN + 4;
    float* sW = (float*)smem;                 // CIN*64
    float* sx = sW + CIN * 64;                // 64*CINP
    const bool isbf = (XMODE == 2) || (XMODE == 1 && *flag != 0u);
    const int tid  = threadIdx.x;
    const int colg = tid & 15;
    const int rowg = tid >> 4;
    const int c0   = colg * 4;
    const int r0l  = rowg * 4;
    const int row0 = bid * 64;

    for (int i = tid * 4; i < CIN * 64; i += 1024)
        *(float4*)&sW[i] = *(const float4*)&W[i];

    const long xbase = (long)row0 * CIN;
    const int  tile  = 64 * CIN;
    const int  limit = (N_NODES - row0) * CIN;   // multiple of 4
    if (isbf) {
        const unsigned short* xb = (const unsigned short*)x + xbase;
        for (int i = tid * 4; i < tile; i += 1024) {
            float4 v = {0.f, 0.f, 0.f, 0.f};
            if (i < limit) {
                ushort4 u = *(const ushort4*)&xb[i];
                v.x = bfbits(u.x); v.y = bfbits(u.y);
                v.z = bfbits(u.z); v.w = bfbits(u.w);
            }
            const int r = i / CIN, k = i & (CIN - 1);
            *(float4*)&sx[r * CINP + k] = v;
        }
    } else {
        const float* xf = (const float*)x + xbase;
        for (int i = tid * 4; i < tile; i += 1024) {
            float4 v = {0.f, 0.f, 0.f, 0.f};
            if (i < limit) v = *(const float4*)&xf[i];
            const int r = i / CIN, k = i & (CIN - 1);
            *(float4*)&sx[r * CINP + k] = v;
        }
    }
    __syncthreads();

    f32x2 acc[4][2];
#pragma unroll
    for (int r = 0; r < 4; ++r) {
        acc[r][0] = (f32x2){0.f, 0.f};
        acc[r][1] = (f32x2){0.f, 0.f};
    }

#pragma unroll 2
    for (int kk = 0; kk < CIN; kk += 4) {
        const float4 w0 = *(const float4*)&sW[(kk + 0) * 64 + c0];
        const float4 w1 = *(const float4*)&sW[(kk + 1) * 64 + c0];
        const float4 w2 = *(const float4*)&sW[(kk + 2) * 64 + c0];
        const float4 w3 = *(const float4*)&sW[(kk + 3) * 64 + c0];
        f32x2 w0lo; w0lo.x = w0.x; w0lo.y = w0.y;
        f32x2 w0hi; w0hi.x = w0.z; w0hi.y = w0.w;
        f32x2 w1lo; w1lo.x = w1.x; w1lo.y = w1.y;
        f32x2 w1hi; w1hi.x = w1.z; w1hi.y = w1.w;
        f32x2 w2lo; w2lo.x = w2.x; w2lo.y = w2.y;
        f32x2 w2hi; w2hi.x = w2.z; w2hi.y = w2.w;
        f32x2 w3lo; w3lo.x = w3.x; w3lo.y = w3.y;
        f32x2 w3hi; w3hi.x = w3.z; w3hi.y = w3.w;
#pragma unroll
        for (int r = 0; r < 4; ++r) {
            const float4 xv = *(const float4*)&sx[(r0l + r) * CINP + kk];
            acc[r][0] = __builtin_elementwise_fma(bcast2(xv.x), w0lo, acc[r][0]);
            acc[r][1] = __builtin_elementwise_fma(bcast2(xv.x), w0hi, acc[r][1]);
            acc[r][0] = __builtin_elementwise_fma(bcast2(xv.y), w1lo, acc[r][0]);
            acc[r][1] = __builtin_elementwise_fma(bcast2(xv.y), w1hi, acc[r][1]);
            acc[r][0] = __builtin_elementwise_fma(bcast2(xv.z), w2lo, acc[r][0]);
            acc[r][1] = __builtin_elementwise_fma(bcast2(xv.z), w2hi, acc[r][1]);
            acc[r][0] = __builtin_elementwise_fma(bcast2(xv.w), w3lo, acc[r][0]);
            acc[r][1] = __builtin_elementwise_fma(bcast2(xv.w), w3hi, acc[r][1]);
        }
    }

    const float4 sa4 = *(const float4*)&a_src[c0];
    const float4 sd4 = *(const float4*)&a_dst[c0];
#pragma unroll
    for (int r = 0; r < 4; ++r) {
        const int row = row0 + r0l + r;
        const float h0 = acc[r][0].x, h1 = acc[r][0].y;
        const float h2 = acc[r][1].x, h3 = acc[r][1].y;
        float vs = fmaf(h0, sa4.x, fmaf(h1, sa4.y, fmaf(h2, sa4.z, h3 * sa4.w)));
        float vd = fmaf(h0, sd4.x, fmaf(h1, sd4.y, fmaf(h2, sd4.z, h3 * sd4.w)));
#pragma unroll
        for (int off = 1; off < 16; off <<= 1) {
            vs += __shfl_xor(vs, off, 64);
            vd += __shfl_xor(vd, off, 64);
        }
        if (row < N_NODES) {
            uint2 u;
            u.x = ((unsigned)__bfloat16_as_ushort(__float2bfloat16(h0))) |
                  (((unsigned)__bfloat16_as_ushort(__float2bfloat16(h1))) << 16);
            u.y = ((unsigned)__bfloat16_as_ushort(__float2bfloat16(h2))) |
                  (((unsigned)__bfloat16_as_ushort(__float2bfloat16(h3))) << 16);
            *(uint2*)&((unsigned short*)hb)[(long)row * 64 + c0] = u;
            if (colg == 0) { as_out[row] = vs; ad_out[row] = vd; }
        }
    }
}

// Standalone gemm (layers 2/3)
template<int CIN, int XMODE>
__global__ __launch_bounds__(256)
void gemm_alpha(const void* __restrict__ x, const float* __restrict__ W,
                const float* __restrict__ a_src, const float* __restrict__ a_dst,
                const unsigned* __restrict__ flag, bf16* __restrict__ hb,
                float* __restrict__ as_out, float* __restrict__ ad_out)
{
    __shared__ __align__(16) unsigned char smem[(CIN * 64 + 64 * (CIN + 4)) * 4];
    gemm_body<CIN, XMODE>(smem, blockIdx.x, x, W, a_src, a_dst, flag, hb, as_out, ad_out);
}

// Fused: binpass blocks first [0, BIN_GRID), then gemm1 blocks.
// Independent work: both depend only on prep; disjoint writes.
__global__ __launch_bounds__(256)
void gemm1_bin(const void* __restrict__ x, const float* __restrict__ W,
               const float* __restrict__ a_src, const float* __restrict__ a_dst,
               const unsigned* __restrict__ flag, bf16* __restrict__ hb,
               float* __restrict__ as_out, float* __restrict__ ad_out,
               const int* __restrict__ ei, int* __restrict__ cur256,
               unsigned* __restrict__ scratch)
{
    __shared__ __align__(16) unsigned char smem[(128 * 64 + 64 * 132) * 4]; // 66560
    if (blockIdx.x < BIN_GRID)
        binpass_body(smem, blockIdx.x, ei, cur256, scratch);
    else
        gemm_body<128, 1>(smem, blockIdx.x - BIN_GRID, x, W, a_src, a_dst,
                          flag, hb, as_out, ad_out);
}

// ---------------- GAT gather: LDS-staged (src,w), no shuffles ---------------
// R7: each 16-lane group stages its node's first <=64 (src, w) pairs into an
// 8KB LDS table (wave-synchronous: writer group == reader group == one wave,
// no barrier). Main loop reads slots with same-address broadcast ds_read_b64
// (4/pass vs R5's 16 ds_bpermute). deg>64 tail computes inline from global.
#define EDGE4_FMA(wX, pX) {                                                  \
    f32x2 w2_ = { wX, wX };                                                  \
    A0 = __builtin_elementwise_fma(w2_, unpk(pX.x), A0);                     \
    A1 = __builtin_elementwise_fma(w2_, unpk(pX.y), A1);                     \
    A2 = __builtin_elementwise_fma(w2_, unpk(pX.z), A2);                     \
    A3 = __builtin_elementwise_fma(w2_, unpk(pX.w), A3); }

template<bool DO_ELU, int OMODE>
__global__ __launch_bounds__(256)
void gat_gather(const int* __restrict__ rowptr,
                const int* __restrict__ csr_src,
                const float* __restrict__ as_in,
                const float* __restrict__ ad_in,
                const unsigned short* __restrict__ hb_in,
                const float* __restrict__ bias,
                void* __restrict__ out,
                const unsigned* __restrict__ flag)
{
    __shared__ int2 s_sw[16 * 64];                 // (src, w) per slot, 8KB
    const int tid  = threadIdx.x;
    const int lane = tid & 63;
    const int l16  = lane & 15;
    const int sub  = l16 >> 3;                     // edge parity slot 0/1
    const int c8   = (l16 & 7) * 8;                // channel group
    const int grp  = tid >> 4;                     // group id in block (0..15)
    const int node = blockIdx.x * 16 + grp;        // grid exact: 3125*16=50000

    const int beg = rowptr[node];
    const int deg = rowptr[node + 1] - beg;
    const float adv = ad_in[node];
    const int nst = (deg < 64) ? deg : 64;

    for (int j = l16; j < nst; j += 16) {
        int s = csr_src[beg + j];
        float v = as_in[s] + adv;
        v = (v > 0.f) ? v : NEG_SLOPE * v;
        s_sw[grp * 64 + j] = make_int2(s, __float_as_int(__expf(fminf(v, 60.f))));
    }
    // group-local LDS, writer wave == reader wave: lgkmcnt ordering suffices

    f32x2 A0 = {0.f, 0.f}, A1 = {0.f, 0.f}, A2 = {0.f, 0.f}, A3 = {0.f, 0.f};
    float dsum = 0.f;

    for (int j0 = 0; j0 < deg; j0 += 8) {
        const int jA = j0 + sub,     jB = j0 + 2 + sub;
        const int jC = j0 + 4 + sub, jD = j0 + 6 + sub;
        const bool vA = jA < deg, vB = jB < deg, vC = jC < deg, vD = jD < deg;
        int sA = 0, sB = 0, sC = 0, sD = 0;
        float wA = 0.f, wB = 0.f, wC = 0.f, wD = 0.f;
        if (vA) {
            if (jA < 64) { int2 t = s_sw[grp * 64 + jA]; sA = t.x; wA = __int_as_float(t.y); }
            else { sA = csr_src[beg + jA]; float v = as_in[sA] + adv;
                   v = (v > 0.f) ? v : NEG_SLOPE * v; wA = __expf(fminf(v, 60.f)); }
        }
        if (vB) {
            if (jB < 64) { int2 t = s_sw[grp * 64 + jB]; sB = t.x; wB = __int_as_float(t.y); }
            else { sB = csr_src[beg + jB]; float v = as_in[sB] + adv;
                   v = (v > 0.f) ? v : NEG_SLOPE * v; wB = __expf(fminf(v, 60.f)); }
        }
        if (vC) {
            if (jC < 64) { int2 t = s_sw[grp * 64 + jC]; sC = t.x; wC = __int_as_float(t.y); }
            else { sC = csr_src[beg + jC]; float v = as_in[sC] + adv;
                   v = (v > 0.f) ? v : NEG_SLOPE * v; wC = __expf(fminf(v, 60.f)); }
        }
        if (vD) {
            if (jD < 64) { int2 t = s_sw[grp * 64 + jD]; sD = t.x; wD = __int_as_float(t.y); }
            else { sD = csr_src[beg + jD]; float v = as_in[sD] + adv;
                   v = (v > 0.f) ? v : NEG_SLOPE * v; wD = __expf(fminf(v, 60.f)); }
        }
        uint4 pA={0u,0u,0u,0u}, pB={0u,0u,0u,0u}, pC={0u,0u,0u,0u}, pD={0u,0u,0u,0u};
        if (vA) pA = *(const uint4*)&hb_in[(long)sA * 64 + c8];
        if (vB) pB = *(const uint4*)&hb_in[(long)sB * 64 + c8];
        if (vC) pC = *(const uint4*)&hb_in[(long)sC * 64 + c8];
        if (vD) pD = *(const uint4*)&hb_in[(long)sD * 64 + c8];
        EDGE4_FMA(wA, pA) EDGE4_FMA(wB, pB) EDGE4_FMA(wC, pC) EDGE4_FMA(wD, pD)
        dsum += (wA + wB) + (wC + wD);
    }

    float a0 = A0.x, a1 = A0.y, a2 = A1.x, a3 = A1.y;
    float a4 = A2.x, a5 = A2.y, a6 = A3.x, a7 = A3.y;
    a0 += __shfl_xor(a0, 8, 64); a1 += __shfl_xor(a1, 8, 64);
    a2 += __shfl_xor(a2, 8, 64); a3 += __shfl_xor(a3, 8, 64);
    a4 += __shfl_xor(a4, 8, 64); a5 += __shfl_xor(a5, 8, 64);
    a6 += __shfl_xor(a6, 8, 64); a7 += __shfl_xor(a7, 8, 64);
    dsum += __shfl_xor(dsum, 8, 64);

    if (sub == 0) {   // lanes l16 0..7 hold channels c8..c8+7
        float inv = 1.f / dsum;
        float r[8] = {a0, a1, a2, a3, a4, a5, a6, a7};
#pragma unroll
        for (int k = 0; k < 8; ++k) {
            r[k] = r[k] * inv + bias[c8 + k];
            if (DO_ELU) r[k] = (r[k] > 0.f) ? r[k] : expm1f(r[k]);
        }
        long o = (long)node * 64 + c8;
        bool bfst = (OMODE == 0) || (*flag != 0u);
        if (bfst) {
            uint4 u;
            u.x = ((unsigned)__bfloat16_as_ushort(__float2bfloat16(r[0]))) |
                  (((unsigned)__bfloat16_as_ushort(__float2bfloat16(r[1]))) << 16);
            u.y = ((unsigned)__bfloat16_as_ushort(__float2bfloat16(r[2]))) |
                  (((unsigned)__bfloat16_as_ushort(__float2bfloat16(r[3]))) << 16);
            u.z = ((unsigned)__bfloat16_as_ushort(__float2bfloat16(r[4]))) |
                  (((unsigned)__bfloat16_as_ushort(__float2bfloat16(r[5]))) << 16);
            u.w = ((unsigned)__bfloat16_as_ushort(__float2bfloat16(r[6]))) |
                  (((unsigned)__bfloat16_as_ushort(__float2bfloat16(r[7]))) << 16);
            *(uint4*)&((unsigned short*)out)[o] = u;
        } else {
            float4 f0 = {r[0], r[1], r[2], r[3]};
            float4 f1 = {r[4], r[5], r[6], r[7]};
            *(float4*)&((float*)out)[o]     = f0;
            *(float4*)&((float*)out)[o + 4] = f1;
        }
    }
}

extern "C" void kernel_launch(void* const* d_in, const int* in_sizes, int n_in,
                              void* d_out, int out_size, void* d_ws, size_t ws_size,
                              hipStream_t stream)
{
    const void* x  = d_in[0];
    const int*  ei = (const int*)d_in[1];
    const void* pW1 = d_in[2],  *pas1 = d_in[3],  *pad1 = d_in[4],  *pb1 = d_in[5];
    const void* pW2 = d_in[6],  *pas2 = d_in[7],  *pad2 = d_in[8],  *pb2 = d_in[9];
    const void* pW3 = d_in[10], *pas3 = d_in[11], *pad3 = d_in[12], *pb3 = d_in[13];

    float* ws = (float*)d_ws;
    bf16*     hbA    = (bf16*)ws;                              // 6.4 MB
    bf16*     hbB    = (bf16*)(ws + (long)N_NODES * 32);       // 6.4 MB
    float*    as_    = ws + (long)N_NODES * 64;
    float*    ad_    = as_ + N_NODES;
    int*      cur256 = (int*)(ad_ + N_NODES);                  // NBUCK
    int*      rowptr = cur256 + NBUCK;                         // N+1
    int*      csr_src= rowptr + N_NODES + 1;                   // 3.4 MB
    unsigned* scratch= (unsigned*)(csr_src + ET_EDGES);        // NBUCK*CAP 6.4 MB
    float*    prm    = (float*)(scratch + (long)NBUCK * CAP);
    unsigned* flag   = (unsigned*)(prm + 20000);

    float* W1 = prm;     float* as1 = W1 + 8192; float* ad1 = as1 + 64; float* b1 = ad1 + 64;
    float* W2 = b1 + 64; float* as2 = W2 + 4096; float* ad2 = as2 + 64; float* b2 = ad2 + 64;
    float* W3 = b2 + 64; float* as3 = W3 + 4096; float* ad3 = as3 + 64; float* b3 = ad3 + 64;

    PrepArgs pa;
    const void* srcs[12] = {pW1, pas1, pad1, pb1, pW2, pas2, pad2, pb2, pW3, pas3, pad3, pb3};
    float*      dsts[12] = {W1, as1, ad1, b1, W2, as2, ad2, b2, W3, as3, ad3, b3};
    int         ns[12]   = {8192, 64, 64, 64, 4096, 64, 64, 64, 4096, 64, 64, 64};
    for (int i = 0; i < 12; ++i) { pa.src[i] = srcs[i]; pa.dst[i] = dsts[i]; pa.n[i] = ns[i]; }
    prep<<<dim3(8, 13), 256, 0, stream>>>(pa, (const unsigned short*)pW1, flag, cur256);

    const int gat_grid = (N_NODES + 15) / 16;   // 3125, exact

    // ---------- Layer 1 GEMM fused with CSR binpass (independent work) ------
    gemm1_bin<<<BIN_GRID + GEMM_GRID, 256, 0, stream>>>(
        x, W1, as1, ad1, flag, hbA, as_, ad_, ei, cur256, scratch);
    fine_scatter<<<NBUCK, 256, 0, stream>>>(cur256, scratch, csr_src, rowptr);
    gat_gather<true, 0><<<gat_grid, 256, 0, stream>>>(
        rowptr, csr_src, as_, ad_, (const unsigned short*)hbA, b1, hbB, flag);

    // ---------- Layer 2 (bf16 layer io) ----------
    gemm_alpha<64, 2><<<GEMM_GRID, 256, 0, stream>>>(
        hbB, W2, as2, ad2, flag, hbA, as_, ad_);
    gat_gather<true, 0><<<gat_grid, 256, 0, stream>>>(
        rowptr, csr_src, as_, ad_, (const unsigned short*)hbA, b2, hbB, flag);

    // ---------- Layer 3 ----------
    gemm_alpha<64, 2><<<GEMM_GRID, 256, 0, stream>>>(
        hbB, W3, as3, ad3, flag, hbA, as_, ad_);
    gat_gather<false, 1><<<gat_grid, 256, 0, stream>>>(
        rowptr, csr_src, as_, ad_, (const unsigned short*)hbA, b3, d_out, flag);
}